// Round 19
// baseline (88.521 us; speedup 1.0000x reference)
//
#include <hip/hip_runtime.h>

typedef unsigned long long u64;

#define L_DIM 4096
#define B_DIM 4
#define KNN 48
#define CAP 384             // survivors/row ~90 (F~2.1% + hi16 extras); 4x margin
#define INVALID_X2 1.0e30f  // encodes mask=0: d^2 ~ 1e30, never selectable
#define VALID_TH 1.0e29f
#define SLACK 8u            // ulp slack on d^2 threshold covering sqrt collisions
#define NT 256
#define NW 4
#define CPT 16              // candidates per thread (NT*CPT = L_DIM)
#define ROWS 2              // query rows per block (same batch; candidates shared)

// ---------------------------------------------------------------------------
// prep: c4 = (x, y, z, valid ? x2 : 1e30); per-batch n_valid via one ballot +
// lane0 atomic per wave (single-address, coalesced-friendly).
// x2 contracted-FMA chain (matches XLA:CPU fused codegen); dot(i,i) == x2(i)
// bit-exact => D[i,i] == 0 exactly.
// ---------------------------------------------------------------------------
__global__ __launch_bounds__(256) void prep_kernel(const float* __restrict__ X,
                                                   const float* __restrict__ mask,
                                                   float4* __restrict__ c4,
                                                   int* __restrict__ nvalid) {
#pragma clang fp contract(off)
    int i = blockIdx.x * 256 + threadIdx.x;              // i in [0, B*L)
    const float4* X4 = (const float4*)X;                 // residue = 3 aligned float4
    float4 a = X4[3 * i];                                // ... f3(=CA x)
    float4 bb = X4[3 * i + 1];                           // f4(=CA y) f5(=CA z) ...
    float x = a.w, y = bb.x, z = bb.y;
    float x2 = __builtin_fmaf(z, z, __builtin_fmaf(y, y, x * x));
    float m = mask[i];
    c4[i] = make_float4(x, y, z, (m > 0.0f) ? x2 : INVALID_X2);
    unsigned long long bal = __ballot(m > 0.0f);
    if ((threadIdx.x & 63) == 0)
        atomicAdd(&nvalid[i >> 12], (int)__popcll(bal));  // block spans one batch
}

// full ascending 64-lane bitonic sort; returns this lane's sorted value
__device__ __forceinline__ unsigned wave_sort64(unsigned sv, int lane) {
#pragma unroll
    for (int k = 2; k <= 64; k <<= 1) {
#pragma unroll
        for (int j = k >> 1; j > 0; j >>= 1) {
            unsigned o = __shfl_xor(sv, j);
            unsigned mn = min(sv, o), mx = max(sv, o);
            bool asc = ((lane & k) == 0);
            bool low = ((lane & j) == 0);
            sv = (asc == low) ? mn : mx;
        }
    }
    return sv;
}

// ---------------------------------------------------------------------------
// main: one block per 2 consecutive rows (same batch), 256 threads.
//  A:  load 16 candidates ONCE; d^2 bits for BOTH rows; per-row thread min;
//      STASH hi-16 of both rows' d^2 bits packed in one u32 in LDS
//      (kills the compiler's phase-C rematerialization of the whole A chain).
//  B:  group-of-4 minima (2 shfl_xor) -> 64/row in LDS -> waves 0/1 sort
//      rows 0/1 concurrently; lane 47 publishes T_r (certified >= q48:
//      each group-min covers 64 candidates; <=47 elements < q48 =>
//      <=47 group-minima < q48 => 48th group-min >= q48). S ~ 88/row.
//  C:  16-bit prefilter from stash: (d2>>16) <= (Tp>>16) is a SUPERSET of
//      {d2 <= Tp} (monotone truncation; extras share T's hi16 bucket, few).
//      Recompute exact d2 only for passers; push exact sqrt key. Final exact
//      rank discards extras => output identical to exact-threshold version.
//  D:  rank-count in (sqrt_bits, idx) order == lax.top_k tie-break, scatter;
//      invalid row -> self-fill. 3 barriers, all LDS deps covered.
// ---------------------------------------------------------------------------
__global__ __launch_bounds__(NT) void knn_kernel(const float4* __restrict__ c4,
                                                 const int* __restrict__ nvalid,
                                                 float* __restrict__ dn,
                                                 float* __restrict__ ei) {
    __shared__ unsigned stash[CPT][NT];  // 16 KB: hi16(d2 row1)|hi16(d2 row0)
    __shared__ unsigned gmin[ROWS][64];  // 512 B: group-of-4 minima per row
    __shared__ u64 surv[ROWS][CAP];      // 6 KB
    __shared__ int cnt[ROWS];
    __shared__ unsigned Tsh[ROWS];

    const int row0 = blockIdx.x * ROWS;
    const int b = row0 >> 12;
    const int i0 = row0 & (L_DIM - 1);
    const int t = threadIdx.x;
    const int w = t >> 6, lane = t & 63;

    // degenerate batch -> both rows self-fill (block-uniform)
    if (nvalid[b] <= KNN) {
        if (w < ROWS && lane < KNN) {
            dn[(size_t)(row0 + w) * KNN + lane] = 0.0f;
            ei[(size_t)(row0 + w) * KNN + lane] = (float)(i0 + w);
        }
        return;
    }

    const float4* cb = c4 + (size_t)b * L_DIM;
    const float4 q0 = cb[i0];                  // broadcast loads
    const float4 q1 = cb[i0 + 1];
    const bool v0 = (q0.w < VALID_TH), v1 = (q1.w < VALID_TH);

    // ---- A: 16 candidates/thread, d^2 bits both rows + 16-bit stash ----
    unsigned rmin0 = 0xFFFFFFFFu, rmin1 = 0xFFFFFFFFu;
    {
#pragma clang fp contract(off)
#pragma unroll
        for (int c = 0; c < CPT; ++c) {
            int j = c * NT + t;
            float4 pj = cb[j];
            float dota = __builtin_fmaf(pj.z, q0.z,
                         __builtin_fmaf(pj.y, q0.y, pj.x * q0.x));
            float dotb = __builtin_fmaf(pj.z, q1.z,
                         __builtin_fmaf(pj.y, q1.y, pj.x * q1.x));
            // fma(-2,dot,t1) == (t1 - 2*dot) bit-exactly (2*dot exact, 1 rounding)
            float d2a = fmaxf(__builtin_fmaf(-2.0f, dota, q0.w + pj.w), 0.0f);
            float d2b = fmaxf(__builtin_fmaf(-2.0f, dotb, q1.w + pj.w), 0.0f);
            unsigned ba = __float_as_uint(d2a);
            unsigned bbts = __float_as_uint(d2b);
            stash[c][t] = (bbts & 0xFFFF0000u) | (ba >> 16);
            rmin0 = min(rmin0, ba);
            rmin1 = min(rmin1, bbts);
        }
    }

    // ---- B: group-of-4 minima -> waves 0/1 sort rows 0/1 ----
    {
        unsigned g0 = min(rmin0, __shfl_xor(rmin0, 1));
        g0 = min(g0, __shfl_xor(g0, 2));
        unsigned g1 = min(rmin1, __shfl_xor(rmin1, 1));
        g1 = min(g1, __shfl_xor(g1, 2));
        if ((lane & 3) == 0) {
            gmin[0][(w << 4) | (lane >> 2)] = g0;
            gmin[1][(w << 4) | (lane >> 2)] = g1;
        }
    }
    if (t < ROWS) cnt[t] = 0;
    __syncthreads();                                   // S1
    if (w < ROWS) {
        unsigned sv = wave_sort64(gmin[w][lane], lane);  // wave w sorts row w
        if (lane == KNN - 1) Tsh[w] = sv;              // 48th-smallest group-min
    }
    __syncthreads();                                   // S2
    const unsigned Tp0 = v0 ? (Tsh[0] + SLACK) : 0u;   // invalid row: none pass
    const unsigned Tp1 = v1 ? (Tsh[1] + SLACK) : 0u;
    const unsigned T16a = Tp0 >> 16, T16b = Tp1 >> 16;

    // ---- C: 16-bit prefilter -> exact recompute for passers -> push ----
    {
#pragma clang fp contract(off)
#pragma unroll
        for (int c = 0; c < CPT; ++c) {
            unsigned v = stash[c][t];
            unsigned ha = v & 0xFFFFu;             // hi16 of row0 d2
            unsigned hb = v >> 16;                 // hi16 of row1 d2
            bool pa = (ha <= T16a) && v0;
            bool pb = (hb <= T16b) && v1;
            if (pa || pb) {                        // rare (~0.7 per thread total)
                int j = c * NT + t;
                float4 pj = cb[j];
                if (pa) {
                    float dota = __builtin_fmaf(pj.z, q0.z,
                                 __builtin_fmaf(pj.y, q0.y, pj.x * q0.x));
                    float d2a = fmaxf(__builtin_fmaf(-2.0f, dota, q0.w + pj.w), 0.0f);
                    int pos = atomicAdd(&cnt[0], 1);
                    if (pos < CAP) {
                        float d = sqrtf(d2a);      // correctly rounded
                        surv[0][pos] = ((u64)__float_as_uint(d) << 32) | (unsigned)j;
                    }
                }
                if (pb) {
                    float dotb = __builtin_fmaf(pj.z, q1.z,
                                 __builtin_fmaf(pj.y, q1.y, pj.x * q1.x));
                    float d2b = fmaxf(__builtin_fmaf(-2.0f, dotb, q1.w + pj.w), 0.0f);
                    int pos = atomicAdd(&cnt[1], 1);
                    if (pos < CAP) {
                        float d = sqrtf(d2b);
                        surv[1][pos] = ((u64)__float_as_uint(d) << 32) | (unsigned)j;
                    }
                }
            }
        }
    }
    __syncthreads();                                   // S3

    // ---- D: per row, block-wide exact rank + scatter (or self-fill) ----
#pragma unroll
    for (int r = 0; r < ROWS; ++r) {
        const bool vr = r ? v1 : v0;
        float* dnrow = dn + (size_t)(row0 + r) * KNN;
        float* eirow = ei + (size_t)(row0 + r) * KNN;
        if (!vr) {                              // block-uniform branch
            if (t < KNN) { dnrow[t] = 0.0f; eirow[t] = (float)(i0 + r); }
        } else {
            int S = cnt[r]; if (S > CAP) S = CAP;
            for (int c = t; c < S; c += NT) {
                u64 key = surv[r][c];
                int rank = 0;
                for (int s = 0; s < S; ++s) rank += (surv[r][s] < key);  // bcast
                if (rank < KNN) {
                    dnrow[rank] = __uint_as_float((unsigned)(key >> 32));
                    eirow[rank] = (float)(key & 0xFFFFFFFFULL);
                }
            }
        }
    }
}

extern "C" void kernel_launch(void* const* d_in, const int* in_sizes, int n_in,
                              void* d_out, int out_size, void* d_ws, size_t ws_size,
                              hipStream_t stream) {
    const float* X = (const float*)d_in[0];
    const float* mask = (const float*)d_in[1];

    float* out = (float*)d_out;
    float* dn = out;                                   // (B,L,K) D_neighbors
    float* ei = out + (size_t)B_DIM * L_DIM * KNN;     // (B,L,K) E_idx as f32

    char* ws = (char*)d_ws;
    float4* c4 = (float4*)ws;                          // 256 KiB
    int* nv = (int*)(ws + (size_t)B_DIM * L_DIM * 16);

    (void)hipMemsetAsync(nv, 0, B_DIM * sizeof(int), stream);
    prep_kernel<<<(B_DIM * L_DIM) / 256, 256, 0, stream>>>(X, mask, c4, nv);
    knn_kernel<<<(B_DIM * L_DIM) / ROWS, NT, 0, stream>>>(c4, nv, dn, ei);
}

// Round 20
// 81.079 us; speedup vs baseline: 1.0918x; 1.0918x over previous
//
#include <hip/hip_runtime.h>

typedef unsigned long long u64;

#define L_DIM 4096
#define B_DIM 4
#define KNN 48
#define CAP 384             // survivors/row ~90 (F~2.1% + hi16 extras); 4x margin
#define INVALID_X2 1.0e30f  // encodes mask=0: d^2 ~ 1e30, never selectable
#define VALID_TH 1.0e29f
#define SLACK 8u            // ulp slack on d^2 threshold covering sqrt collisions
#define NT 256
#define NW 4
#define CPT 16              // candidates per thread (NT*CPT = L_DIM)
#define ROWS 2              // query rows per block (same batch; candidates shared)

// ---------------------------------------------------------------------------
// prep: c4 = (x, y, z, valid ? x2 : 1e30); per-batch n_valid via one ballot +
// lane0 atomic per wave (single-address, coalesced-friendly).
// x2 contracted-FMA chain (matches XLA:CPU fused codegen); dot(i,i) == x2(i)
// bit-exact => D[i,i] == 0 exactly.
// ---------------------------------------------------------------------------
__global__ __launch_bounds__(256) void prep_kernel(const float* __restrict__ X,
                                                   const float* __restrict__ mask,
                                                   float4* __restrict__ c4,
                                                   int* __restrict__ nvalid) {
#pragma clang fp contract(off)
    int i = blockIdx.x * 256 + threadIdx.x;              // i in [0, B*L)
    const float4* X4 = (const float4*)X;                 // residue = 3 aligned float4
    float4 a = X4[3 * i];                                // ... f3(=CA x)
    float4 bb = X4[3 * i + 1];                           // f4(=CA y) f5(=CA z) ...
    float x = a.w, y = bb.x, z = bb.y;
    float x2 = __builtin_fmaf(z, z, __builtin_fmaf(y, y, x * x));
    float m = mask[i];
    c4[i] = make_float4(x, y, z, (m > 0.0f) ? x2 : INVALID_X2);
    unsigned long long bal = __ballot(m > 0.0f);
    if ((threadIdx.x & 63) == 0)
        atomicAdd(&nvalid[i >> 12], (int)__popcll(bal));  // block spans one batch
}

// full ascending 64-lane bitonic sort; returns this lane's sorted value
__device__ __forceinline__ unsigned wave_sort64(unsigned sv, int lane) {
#pragma unroll
    for (int k = 2; k <= 64; k <<= 1) {
#pragma unroll
        for (int j = k >> 1; j > 0; j >>= 1) {
            unsigned o = __shfl_xor(sv, j);
            unsigned mn = min(sv, o), mx = max(sv, o);
            bool asc = ((lane & k) == 0);
            bool low = ((lane & j) == 0);
            sv = (asc == low) ? mn : mx;
        }
    }
    return sv;
}

// ---------------------------------------------------------------------------
// main: one block per 2 consecutive rows (same batch), 256 threads.
//  A:  load 16 candidates ONCE; d^2 bits for BOTH rows; per-row thread min;
//      pack hi16(row1 d2)|hi16(row0 d2) into 16 REGISTERS, made opaque via
//      asm "+v" so the compiler cannot rematerialize the A chain in C.
//  B:  group-of-4 minima (2 shfl_xor) -> 64/row in LDS -> waves 0/1 sort
//      rows 0/1 concurrently; lane 47 publishes T_r (certified >= q48:
//      each group-min covers 64 candidates; <=47 elements < q48 =>
//      <=47 group-minima < q48 => 48th group-min >= q48). S ~ 88/row.
//  C:  16-bit register prefilter: (d2>>16) <= (Tp>>16) is a SUPERSET of
//      {d2 <= Tp} (monotone truncation; extras share T's hi16 bucket, few).
//      Reload + exact recompute only for passers (~0.7/thread); push exact
//      sqrt key. Final exact rank discards extras => output identical.
//  D:  rank-count in (sqrt_bits, idx) order == lax.top_k tie-break, scatter;
//      invalid row -> self-fill. 3 barriers, all LDS deps covered.
// ---------------------------------------------------------------------------
__global__ __launch_bounds__(NT) void knn_kernel(const float4* __restrict__ c4,
                                                 const int* __restrict__ nvalid,
                                                 float* __restrict__ dn,
                                                 float* __restrict__ ei) {
    __shared__ unsigned gmin[ROWS][64];  // 512 B: group-of-4 minima per row
    __shared__ u64 surv[ROWS][CAP];      // 6 KB
    __shared__ int cnt[ROWS];
    __shared__ unsigned Tsh[ROWS];

    const int row0 = blockIdx.x * ROWS;
    const int b = row0 >> 12;
    const int i0 = row0 & (L_DIM - 1);
    const int t = threadIdx.x;
    const int w = t >> 6, lane = t & 63;

    // degenerate batch -> both rows self-fill (block-uniform)
    if (nvalid[b] <= KNN) {
        if (w < ROWS && lane < KNN) {
            dn[(size_t)(row0 + w) * KNN + lane] = 0.0f;
            ei[(size_t)(row0 + w) * KNN + lane] = (float)(i0 + w);
        }
        return;
    }

    const float4* cb = c4 + (size_t)b * L_DIM;
    const float4 q0 = cb[i0];                  // broadcast loads
    const float4 q1 = cb[i0 + 1];
    const bool v0 = (q0.w < VALID_TH), v1 = (q1.w < VALID_TH);

    // ---- A: 16 candidates/thread, d^2 bits both rows + packed reg stash ----
    unsigned pk[CPT];
    unsigned rmin0 = 0xFFFFFFFFu, rmin1 = 0xFFFFFFFFu;
    {
#pragma clang fp contract(off)
#pragma unroll
        for (int c = 0; c < CPT; ++c) {
            int j = c * NT + t;
            float4 pj = cb[j];
            float dota = __builtin_fmaf(pj.z, q0.z,
                         __builtin_fmaf(pj.y, q0.y, pj.x * q0.x));
            float dotb = __builtin_fmaf(pj.z, q1.z,
                         __builtin_fmaf(pj.y, q1.y, pj.x * q1.x));
            // fma(-2,dot,t1) == (t1 - 2*dot) bit-exactly (2*dot exact, 1 rounding)
            float d2a = fmaxf(__builtin_fmaf(-2.0f, dota, q0.w + pj.w), 0.0f);
            float d2b = fmaxf(__builtin_fmaf(-2.0f, dotb, q1.w + pj.w), 0.0f);
            unsigned ba = __float_as_uint(d2a);
            unsigned bbts = __float_as_uint(d2b);
            pk[c] = (bbts & 0xFFFF0000u) | (ba >> 16);
            rmin0 = min(rmin0, ba);
            rmin1 = min(rmin1, bbts);
        }
        // opaque barrier: forces pk[] to live in VGPRs; compiler cannot
        // rematerialize the distance chains through it (rule #17 idiom)
#pragma unroll
        for (int c = 0; c < CPT; ++c)
            asm volatile("" : "+v"(pk[c]));
    }

    // ---- B: group-of-4 minima -> waves 0/1 sort rows 0/1 ----
    {
        unsigned g0 = min(rmin0, __shfl_xor(rmin0, 1));
        g0 = min(g0, __shfl_xor(g0, 2));
        unsigned g1 = min(rmin1, __shfl_xor(rmin1, 1));
        g1 = min(g1, __shfl_xor(g1, 2));
        if ((lane & 3) == 0) {
            gmin[0][(w << 4) | (lane >> 2)] = g0;
            gmin[1][(w << 4) | (lane >> 2)] = g1;
        }
    }
    if (t < ROWS) cnt[t] = 0;
    __syncthreads();                                   // S1
    if (w < ROWS) {
        unsigned sv = wave_sort64(gmin[w][lane], lane);  // wave w sorts row w
        if (lane == KNN - 1) Tsh[w] = sv;              // 48th-smallest group-min
    }
    __syncthreads();                                   // S2
    const unsigned Tp0 = v0 ? (Tsh[0] + SLACK) : 0u;   // invalid row: none pass
    const unsigned Tp1 = v1 ? (Tsh[1] + SLACK) : 0u;
    const unsigned T16a = Tp0 >> 16, T16b = Tp1 >> 16;

    // ---- C: register prefilter -> exact recompute for passers -> push ----
    {
#pragma clang fp contract(off)
#pragma unroll
        for (int c = 0; c < CPT; ++c) {
            unsigned ha = pk[c] & 0xFFFFu;         // hi16 of row0 d2
            unsigned hb = pk[c] >> 16;             // hi16 of row1 d2
            bool pa = v0 && (ha <= T16a);
            bool pb = v1 && (hb <= T16b);
            if (pa || pb) {                        // rare (~0.7 per thread total)
                int j = c * NT + t;
                float4 pj = cb[j];
                if (pa) {
                    float dota = __builtin_fmaf(pj.z, q0.z,
                                 __builtin_fmaf(pj.y, q0.y, pj.x * q0.x));
                    float d2a = fmaxf(__builtin_fmaf(-2.0f, dota, q0.w + pj.w), 0.0f);
                    int pos = atomicAdd(&cnt[0], 1);
                    if (pos < CAP) {
                        float d = sqrtf(d2a);      // correctly rounded
                        surv[0][pos] = ((u64)__float_as_uint(d) << 32) | (unsigned)j;
                    }
                }
                if (pb) {
                    float dotb = __builtin_fmaf(pj.z, q1.z,
                                 __builtin_fmaf(pj.y, q1.y, pj.x * q1.x));
                    float d2b = fmaxf(__builtin_fmaf(-2.0f, dotb, q1.w + pj.w), 0.0f);
                    int pos = atomicAdd(&cnt[1], 1);
                    if (pos < CAP) {
                        float d = sqrtf(d2b);
                        surv[1][pos] = ((u64)__float_as_uint(d) << 32) | (unsigned)j;
                    }
                }
            }
        }
    }
    __syncthreads();                                   // S3

    // ---- D: per row, block-wide exact rank + scatter (or self-fill) ----
#pragma unroll
    for (int r = 0; r < ROWS; ++r) {
        const bool vr = r ? v1 : v0;
        float* dnrow = dn + (size_t)(row0 + r) * KNN;
        float* eirow = ei + (size_t)(row0 + r) * KNN;
        if (!vr) {                              // block-uniform branch
            if (t < KNN) { dnrow[t] = 0.0f; eirow[t] = (float)(i0 + r); }
        } else {
            int S = cnt[r]; if (S > CAP) S = CAP;
            for (int c = t; c < S; c += NT) {
                u64 key = surv[r][c];
                int rank = 0;
                for (int s = 0; s < S; ++s) rank += (surv[r][s] < key);  // bcast
                if (rank < KNN) {
                    dnrow[rank] = __uint_as_float((unsigned)(key >> 32));
                    eirow[rank] = (float)(key & 0xFFFFFFFFULL);
                }
            }
        }
    }
}

extern "C" void kernel_launch(void* const* d_in, const int* in_sizes, int n_in,
                              void* d_out, int out_size, void* d_ws, size_t ws_size,
                              hipStream_t stream) {
    const float* X = (const float*)d_in[0];
    const float* mask = (const float*)d_in[1];

    float* out = (float*)d_out;
    float* dn = out;                                   // (B,L,K) D_neighbors
    float* ei = out + (size_t)B_DIM * L_DIM * KNN;     // (B,L,K) E_idx as f32

    char* ws = (char*)d_ws;
    float4* c4 = (float4*)ws;                          // 256 KiB
    int* nv = (int*)(ws + (size_t)B_DIM * L_DIM * 16);

    (void)hipMemsetAsync(nv, 0, B_DIM * sizeof(int), stream);
    prep_kernel<<<(B_DIM * L_DIM) / 256, 256, 0, stream>>>(X, mask, c4, nv);
    knn_kernel<<<(B_DIM * L_DIM) / ROWS, NT, 0, stream>>>(c4, nv, dn, ei);
}

// Round 21
// 69.957 us; speedup vs baseline: 1.2654x; 1.1590x over previous
//
#include <hip/hip_runtime.h>

typedef unsigned long long u64;

#define L_DIM 4096
#define B_DIM 4
#define KNN 48
#define CAP 512             // survivors/row ~88 (F~2.1%); 5.8x margin
#define INVALID_X2 1.0e30f  // encodes mask=0: d^2 ~ 1e30, never selectable
#define VALID_TH 1.0e29f
#define SLACK 8u            // ulp slack on d^2 threshold covering sqrt collisions
#define NT 256
#define NW 4
#define CPT 16              // candidates per thread (NT*CPT = L_DIM)
#define ROWS 2              // query rows per block (same batch; candidates shared)

// ---------------------------------------------------------------------------
// prep: c4 = (x, y, z, valid ? x2 : 1e30); per-batch n_valid via one ballot +
// lane0 atomic per wave (single-address, coalesced-friendly).
// x2 contracted-FMA chain (matches XLA:CPU fused codegen); dot(i,i) == x2(i)
// bit-exact => D[i,i] == 0 exactly.
// ---------------------------------------------------------------------------
__global__ __launch_bounds__(256) void prep_kernel(const float* __restrict__ X,
                                                   const float* __restrict__ mask,
                                                   float4* __restrict__ c4,
                                                   int* __restrict__ nvalid) {
#pragma clang fp contract(off)
    int i = blockIdx.x * 256 + threadIdx.x;              // i in [0, B*L)
    const float4* X4 = (const float4*)X;                 // residue = 3 aligned float4
    float4 a = X4[3 * i];                                // ... f3(=CA x)
    float4 bb = X4[3 * i + 1];                           // f4(=CA y) f5(=CA z) ...
    float x = a.w, y = bb.x, z = bb.y;
    float x2 = __builtin_fmaf(z, z, __builtin_fmaf(y, y, x * x));
    float m = mask[i];
    c4[i] = make_float4(x, y, z, (m > 0.0f) ? x2 : INVALID_X2);
    unsigned long long bal = __ballot(m > 0.0f);
    if ((threadIdx.x & 63) == 0)
        atomicAdd(&nvalid[i >> 12], (int)__popcll(bal));  // block spans one batch
}

// full ascending 64-lane bitonic sort; returns this lane's sorted value
__device__ __forceinline__ unsigned wave_sort64(unsigned sv, int lane) {
#pragma unroll
    for (int k = 2; k <= 64; k <<= 1) {
#pragma unroll
        for (int j = k >> 1; j > 0; j >>= 1) {
            unsigned o = __shfl_xor(sv, j);
            unsigned mn = min(sv, o), mx = max(sv, o);
            bool asc = ((lane & k) == 0);
            bool low = ((lane & j) == 0);
            sv = (asc == low) ? mn : mx;
        }
    }
    return sv;
}

// ---------------------------------------------------------------------------
// main: one block per 2 consecutive rows (same batch), 256 threads.
//  A:  load 16 candidates ONCE; d^2 bits for BOTH rows; per-row thread min.
//  B:  group-of-4 minima (2 shfl_xor) -> 64/row in LDS -> waves 0/1 sort
//      rows 0/1 concurrently; lane 47 publishes T_r.
//      Cert: each group-min covers 64 candidates; <=47 elements < q48 =>
//      <=47 group-minima < q48 => 48th group-min >= q48. S ~ 88/row.
//  C:  compact survivors (d2 <= T+SLACK bit-domain), exact sqrt key at push.
//  D:  WAVE-SPLIT: waves 0-1 rank+scatter row 0 while waves 2-3 do row 1
//      concurrently (r14 did both rows serially on waves 0-1 with 2-3 idle).
//      Rank-count in (sqrt_bits, idx) order == lax.top_k tie-break;
//      invalid row -> self-fill. 3 barriers, all LDS deps covered.
// ---------------------------------------------------------------------------
__global__ __launch_bounds__(NT) void knn_kernel(const float4* __restrict__ c4,
                                                 const int* __restrict__ nvalid,
                                                 float* __restrict__ dn,
                                                 float* __restrict__ ei) {
    __shared__ unsigned gmin[ROWS][64];  // 512 B: group-of-4 minima per row
    __shared__ u64 surv[ROWS][CAP];      // 8 KB
    __shared__ int cnt[ROWS];
    __shared__ unsigned Tsh[ROWS];

    const int row0 = blockIdx.x * ROWS;
    const int b = row0 >> 12;
    const int i0 = row0 & (L_DIM - 1);
    const int t = threadIdx.x;
    const int w = t >> 6, lane = t & 63;

    // degenerate batch -> both rows self-fill (block-uniform)
    if (nvalid[b] <= KNN) {
        if (w < ROWS && lane < KNN) {
            dn[(size_t)(row0 + w) * KNN + lane] = 0.0f;
            ei[(size_t)(row0 + w) * KNN + lane] = (float)(i0 + w);
        }
        return;
    }

    const float4* cb = c4 + (size_t)b * L_DIM;
    const float4 q0 = cb[i0];                  // broadcast loads
    const float4 q1 = cb[i0 + 1];
    const bool v0 = (q0.w < VALID_TH), v1 = (q1.w < VALID_TH);

    // ---- A: 16 candidates/thread, d^2 bits for both rows ----
    unsigned d20[CPT], d21[CPT];
    unsigned rmin0 = 0xFFFFFFFFu, rmin1 = 0xFFFFFFFFu;
    {
#pragma clang fp contract(off)
#pragma unroll
        for (int c = 0; c < CPT; ++c) {
            int j = c * NT + t;
            float4 pj = cb[j];
            float dota = __builtin_fmaf(pj.z, q0.z,
                         __builtin_fmaf(pj.y, q0.y, pj.x * q0.x));
            float dotb = __builtin_fmaf(pj.z, q1.z,
                         __builtin_fmaf(pj.y, q1.y, pj.x * q1.x));
            // fma(-2,dot,t1) == (t1 - 2*dot) bit-exactly (2*dot exact, 1 rounding)
            float d2a = fmaxf(__builtin_fmaf(-2.0f, dota, q0.w + pj.w), 0.0f);
            float d2b = fmaxf(__builtin_fmaf(-2.0f, dotb, q1.w + pj.w), 0.0f);
            d20[c] = __float_as_uint(d2a);
            d21[c] = __float_as_uint(d2b);
            rmin0 = min(rmin0, d20[c]);
            rmin1 = min(rmin1, d21[c]);
        }
    }

    // ---- B: group-of-4 minima -> waves 0/1 sort rows 0/1 ----
    {
        unsigned g0 = min(rmin0, __shfl_xor(rmin0, 1));
        g0 = min(g0, __shfl_xor(g0, 2));
        unsigned g1 = min(rmin1, __shfl_xor(rmin1, 1));
        g1 = min(g1, __shfl_xor(g1, 2));
        if ((lane & 3) == 0) {
            gmin[0][(w << 4) | (lane >> 2)] = g0;
            gmin[1][(w << 4) | (lane >> 2)] = g1;
        }
    }
    if (t < ROWS) cnt[t] = 0;
    __syncthreads();                                   // S1
    if (w < ROWS) {
        unsigned sv = wave_sort64(gmin[w][lane], lane);  // wave w sorts row w
        if (lane == KNN - 1) Tsh[w] = sv;              // 48th-smallest group-min
    }
    __syncthreads();                                   // S2
    const unsigned Tp0 = v0 ? (Tsh[0] + SLACK) : 0u;   // invalid row: no survivors
    const unsigned Tp1 = v1 ? (Tsh[1] + SLACK) : 0u;

    // ---- C: compact survivors per row, exact sqrt key at push time ----
#pragma unroll
    for (int c = 0; c < CPT; ++c) {
        unsigned j = (unsigned)(c * NT + t);
        if (d20[c] <= Tp0) {
            int pos = atomicAdd(&cnt[0], 1);
            if (pos < CAP) {
                float d = sqrtf(__uint_as_float(d20[c]));   // correctly rounded
                surv[0][pos] = ((u64)__float_as_uint(d) << 32) | j;
            }
        }
        if (d21[c] <= Tp1) {
            int pos = atomicAdd(&cnt[1], 1);
            if (pos < CAP) {
                float d = sqrtf(__uint_as_float(d21[c]));
                surv[1][pos] = ((u64)__float_as_uint(d) << 32) | j;
            }
        }
    }
    __syncthreads();                                   // S3

    // ---- D: WAVE-SPLIT exact rank + scatter (half-block per row) ----
    {
        const int r = t >> 7;                  // waves 0-1 -> row 0; 2-3 -> row 1
        const int tl = t & 127;
        const bool vr = r ? v1 : v0;
        float* dnrow = dn + (size_t)(row0 + r) * KNN;
        float* eirow = ei + (size_t)(row0 + r) * KNN;
        if (!vr) {                              // half-block-uniform branch
            if (tl < KNN) { dnrow[tl] = 0.0f; eirow[tl] = (float)(i0 + r); }
        } else {
            int S = cnt[r]; if (S > CAP) S = CAP;
            for (int c = tl; c < S; c += 128) {
                u64 key = surv[r][c];
                int rank = 0;
                for (int s = 0; s < S; ++s) rank += (surv[r][s] < key);  // bcast
                if (rank < KNN) {
                    dnrow[rank] = __uint_as_float((unsigned)(key >> 32));
                    eirow[rank] = (float)(key & 0xFFFFFFFFULL);
                }
            }
        }
    }
}

extern "C" void kernel_launch(void* const* d_in, const int* in_sizes, int n_in,
                              void* d_out, int out_size, void* d_ws, size_t ws_size,
                              hipStream_t stream) {
    const float* X = (const float*)d_in[0];
    const float* mask = (const float*)d_in[1];

    float* out = (float*)d_out;
    float* dn = out;                                   // (B,L,K) D_neighbors
    float* ei = out + (size_t)B_DIM * L_DIM * KNN;     // (B,L,K) E_idx as f32

    char* ws = (char*)d_ws;
    float4* c4 = (float4*)ws;                          // 256 KiB
    int* nv = (int*)(ws + (size_t)B_DIM * L_DIM * 16);

    (void)hipMemsetAsync(nv, 0, B_DIM * sizeof(int), stream);
    prep_kernel<<<(B_DIM * L_DIM) / 256, 256, 0, stream>>>(X, mask, c4, nv);
    knn_kernel<<<(B_DIM * L_DIM) / ROWS, NT, 0, stream>>>(c4, nv, dn, ei);
}